// Round 5
// baseline (410.192 us; speedup 1.0000x reference)
//
#include <hip/hip_runtime.h>
#include <math.h>

#define BATCH 8
#define CH    64
#define NPTS  2048
#define KNN   20
#define OUTC  64

// Branchless sorted insert (ascending d[0..19], d[0] = 20th best).
// Precondition: iv > d[0].
__device__ __forceinline__ void ladder20(float (&d)[KNN], int (&id)[KNN], float iv, int ii) {
    bool ci = true;
    #pragma unroll
    for (int s = 0; s < KNN; ++s) {
        const bool  cn = (s < KNN-1) ? (iv > d[s+1]) : false;
        const float dn = (s < KNN-1) ? d[s+1] : 0.f;
        const int   gn = (s < KNN-1) ? id[s+1] : 0;
        d[s]  = cn ? dn : (ci ? iv : d[s]);
        id[s] = cn ? gn : (ci ? ii : id[s]);
        ci = cn;
    }
}

// prep: 512 blocks, 32-m tiles.
// y1t[b][m][o] = W1 . x[:,m] ; zt[b][n][o] = (W2-W1) . x[:,n] + bias ; xx = ||x_m||^2
__global__ __launch_bounds__(256) void edgeconv_prep(
    const float* __restrict__ x, const float* __restrict__ W,
    const float* __restrict__ bias,
    float* __restrict__ y1t, float* __restrict__ zt, float* __restrict__ xx)
{
    __shared__ __align__(16) float Wt1[64*65];   // [c][o] pad 65 (conflict-free)
    __shared__ __align__(16) float Wtd[64*65];
    __shared__ __align__(16) float xs [64*32];   // [c][m]
    const int tx  = threadIdx.x;
    const int bid = blockIdx.x;
    const int b   = bid >> 6;
    const int m0  = (bid & 63) << 5;
    const float* xb = x + (size_t)b * (CH * NPTS);

    {   // stage W transposed (pad 65)
        const int o  = tx >> 2;
        const int cb = (tx & 3) << 4;
        #pragma unroll
        for (int cc = 0; cc < 16; cc += 4) {
            const float4 w1 = *(const float4*)&W[o*128 + cb + cc];
            const float4 w2 = *(const float4*)&W[o*128 + 64 + cb + cc];
            const float a1[4] = {w1.x, w1.y, w1.z, w1.w};
            const float a2[4] = {w2.x, w2.y, w2.z, w2.w};
            #pragma unroll
            for (int e = 0; e < 4; ++e) {
                Wt1[(cb+cc+e)*65 + o] = a1[e];
                Wtd[(cb+cc+e)*65 + o] = a2[e] - a1[e];
            }
        }
    }
    {   // stage x tile [64c][32m]
        const int c0 = tx >> 2;
        const int j0 = (tx & 3) << 3;
        *(float4*)&xs[c0*32 + j0]     = *(const float4*)&xb[(size_t)c0*NPTS + m0 + j0];
        *(float4*)&xs[c0*32 + j0 + 4] = *(const float4*)&xb[(size_t)c0*NPTS + m0 + j0 + 4];
    }
    __syncthreads();

    if (tx < 32) {   // squared norms
        float s = 0.f;
        #pragma unroll
        for (int c = 0; c < 64; ++c) { const float v = xs[c*32 + tx]; s = fmaf(v, v, s); }
        xx[b*NPTS + m0 + tx] = s;
    }

    const int o  = tx & 63;   // lane = output channel (coalesced writes)
    const int mg = tx >> 6;   // wave -> 8-m chunk
    float y[8], z[8];
    const float bo = bias[o];
    #pragma unroll
    for (int i = 0; i < 8; ++i) { y[i] = 0.f; z[i] = bo; }
    #pragma unroll 8
    for (int c = 0; c < 64; ++c) {
        const float w1 = Wt1[c*65 + o];
        const float wd = Wtd[c*65 + o];
        float a[8];
        *(float4*)&a[0] = *(const float4*)&xs[c*32 + mg*8];
        *(float4*)&a[4] = *(const float4*)&xs[c*32 + mg*8 + 4];
        #pragma unroll
        for (int i = 0; i < 8; ++i) {
            y[i] = fmaf(w1, a[i], y[i]);
            z[i] = fmaf(wd, a[i], z[i]);
        }
    }
    #pragma unroll
    for (int i = 0; i < 8; ++i) {
        const int m = m0 + mg*8 + i;
        y1t[((size_t)b*NPTS + m)*64 + o] = y[i];
        zt [((size_t)b*NPTS + m)*64 + o] = z[i];
    }
}

// Main: fused kNN + gather + lrelu + max. 512 blocks = (batch, 32-row tile).
// Rank key: 2*dot(n,m) - ||x_m||^2. Thread (r=tx>>3, q=tx&7) computes AND scans
// scores for row r, cols q*8..q*8+8 of each 64-m tile — no S transpose needed.
// Row-shared threshold thrR = max over row's 8 lanes of own 20th-best (safe,
// exact: every thr contributor has an earlier index; strict-> drop == lax.top_k).
__global__ __launch_bounds__(256) void edgeconv_main(
    const float* __restrict__ x,
    const float* __restrict__ y1t, const float* __restrict__ zt,
    const float* __restrict__ xx, float* __restrict__ out)
{
    __shared__ __align__(16) char pool[43520];
    float* xn  = (float*)pool;              // [64c][32r]   8192
    float* xmb = (float*)(pool + 8192);     // [2][64c][64m] 32768 (double buffer)
    float* xxb = (float*)(pool + 40960);    // [2][64]      512
    // phase-2 aliases (phase-1 data dead at first touch, barrier-separated):
    float* mv  = (float*)pool;              // [256 lanes][20] values
    int*   mi  = (int*)(pool + 20480);      // [256 lanes][20] indices
    int*   ml  = (int*)(pool + 40960);      // [32][20] merged knn idx
    float* outbuf = (float*)pool;           // [32][68] epilogue staging

    const int tx  = threadIdx.x;
    const int bid = blockIdx.x;
    const int b   = bid >> 6;
    const int n0  = (bid & 63) << 5;
    const float* xb = x + (size_t)b * (CH * NPTS);

    {   // stage xn [64c][32r]
        const int c0 = tx >> 2;
        const int j0 = (tx & 3) << 3;
        *(float4*)&xn[c0*32 + j0]     = *(const float4*)&xb[(size_t)c0*NPTS + n0 + j0];
        *(float4*)&xn[c0*32 + j0 + 4] = *(const float4*)&xb[(size_t)c0*NPTS + n0 + j0 + 4];
    }
    {   // stage xm buffer 0 (m-tile 0) + xx
        const int c = tx >> 4;
        const int j = (tx & 15) << 2;
        #pragma unroll
        for (int it = 0; it < 4; ++it)
            *(float4*)&xmb[(c + it*16)*64 + j] = *(const float4*)&xb[(size_t)(c + it*16)*NPTS + j];
        if (tx < 64) xxb[tx] = xx[b*NPTS + tx];
    }

    const int r = tx >> 3;          // my row (0..31)
    const int q = tx & 7;           // my col-octet
    float d[KNN]; int id[KNN];
    #pragma unroll
    for (int k = 0; k < KNN; ++k) { d[k] = -INFINITY; id[k] = 0; }
    float thrR = -INFINITY;

    for (int t = 0; t < 32; ++t) {
        __syncthreads();            // buf[cur] ready; all reads of buf[cur^1] from t-1 done
        const int cur = t & 1;
        const float* bufc = xmb + cur*4096;
        const float* xxc  = xxb + cur*64;
        float* bufn = xmb + (cur^1)*4096;
        float* xxn  = xxb + (cur^1)*64;

        // issue prefetch of next m-tile (global, latency hidden under Gram)
        float4 p0, p1, p2, p3;
        float xxp = 0.f;
        const int tn  = t + 1;
        const int jj  = (tx & 15) << 2;
        const int cc4 = tx >> 4;
        if (tn < 32) {
            const int mb2 = tn << 6;
            p0 = *(const float4*)&xb[(size_t)(cc4 +  0)*NPTS + mb2 + jj];
            p1 = *(const float4*)&xb[(size_t)(cc4 + 16)*NPTS + mb2 + jj];
            p2 = *(const float4*)&xb[(size_t)(cc4 + 32)*NPTS + mb2 + jj];
            p3 = *(const float4*)&xb[(size_t)(cc4 + 48)*NPTS + mb2 + jj];
            if (tx < 64) xxp = xx[b*NPTS + mb2 + tx];
        }

        // Gram: acc8[e] = dot(x_n[r], x_m[q*8+e])  — xn read broadcast (8 lanes/row)
        float acc8[8];
        #pragma unroll
        for (int e = 0; e < 8; ++e) acc8[e] = 0.f;
        #pragma unroll 8
        for (int c = 0; c < 64; ++c) {
            const float av = xn[c*32 + r];
            float bv[8];
            *(float4*)&bv[0] = *(const float4*)&bufc[c*64 + q*8];
            *(float4*)&bv[4] = *(const float4*)&bufc[c*64 + q*8 + 4];
            #pragma unroll
            for (int e = 0; e < 8; ++e) acc8[e] = fmaf(av, bv[e], acc8[e]);
        }

        // keys + candidate mask (strict > : lax.top_k tie semantics)
        float xq[8];
        *(float4*)&xq[0] = *(const float4*)&xxc[q*8];
        *(float4*)&xq[4] = *(const float4*)&xxc[q*8 + 4];
        float v[8];
        unsigned msk = 0u;
        #pragma unroll
        for (int e = 0; e < 8; ++e) {
            v[e] = fmaf(2.f, acc8[e], -xq[e]);
            msk |= (v[e] > thrR) ? (1u << e) : 0u;
        }

        // drain: wave pays max-lane candidate count; values muxed from REGISTERS
        const int mb = (t << 6) + (q << 3);
        while (__any(msk != 0u)) {
            const bool act = (msk != 0u);
            const int  e   = __ffs(msk) - 1;    // ascending e => ascending m (tie order)
            msk &= msk - 1u;
            const float t01 = (e & 1) ? v[1] : v[0];
            const float t23 = (e & 1) ? v[3] : v[2];
            const float t45 = (e & 1) ? v[5] : v[4];
            const float t67 = (e & 1) ? v[7] : v[6];
            const float t03 = (e & 2) ? t23 : t01;
            const float t47 = (e & 2) ? t67 : t45;
            const float vv  = (e & 4) ? t47 : t03;
            if (act && vv > d[0]) ladder20(d, id, vv, mb + e);
        }

        // row-shared threshold: max over the row's 8 lanes of own d[0]
        float tm = d[0];
        tm = fmaxf(tm, __shfl_xor(tm, 1));
        tm = fmaxf(tm, __shfl_xor(tm, 2));
        tm = fmaxf(tm, __shfl_xor(tm, 4));
        thrR = tm;

        if (tn < 32) {   // commit prefetched tile into the other buffer
            *(float4*)&bufn[(cc4 +  0)*64 + jj] = p0;
            *(float4*)&bufn[(cc4 + 16)*64 + jj] = p1;
            *(float4*)&bufn[(cc4 + 32)*64 + jj] = p2;
            *(float4*)&bufn[(cc4 + 48)*64 + jj] = p3;
            if (tx < 64) xxn[tx] = xxp;
        }
    }
    __syncthreads();   // all Gram reads done; pool reusable

    // dump per-lane sorted lists (scalar stores keep d/id in registers)
    #pragma unroll
    for (int k = 0; k < KNN; ++k) { mv[tx*20 + k] = d[k]; mi[tx*20 + k] = id[k]; }
    __syncthreads();

    // 8-head merge, one lane per row; comparator (v desc, idx asc) == lax.top_k
    if (q == 0) {
        float hv[8]; int hi[8]; int hp[8];
        #pragma unroll
        for (int s = 0; s < 8; ++s) {
            hp[s] = KNN - 1;
            hv[s] = mv[(r*8 + s)*20 + KNN - 1];
            hi[s] = mi[(r*8 + s)*20 + KNN - 1];
        }
        for (int k = 0; k < KNN; ++k) {
            float bv = hv[0]; int bg = hi[0]; int bs = 0;
            #pragma unroll
            for (int s = 1; s < 8; ++s) {
                const bool better = (hv[s] > bv) || (hv[s] == bv && hi[s] < bg);
                bv = better ? hv[s] : bv;
                bg = better ? hi[s] : bg;
                bs = better ? s : bs;
            }
            ml[r*20 + k] = bg;
            #pragma unroll
            for (int s = 0; s < 8; ++s) {     // static-index advance (rule #20)
                if (bs == s) {
                    const int np  = hp[s] - 1;
                    hp[s] = np;
                    const bool ok = (np >= 0);
                    const int npc = ok ? np : 0;
                    const float nv = mv[(r*8 + s)*20 + npc];
                    const int   ng = mi[(r*8 + s)*20 + npc];
                    hv[s] = ok ? nv : -INFINITY;
                    hi[s] = ok ? ng : 0;
                }
            }
        }
    }
    __syncthreads();

    // epilogue: out[b,o,n] = max_k lrelu(y1t[m_k][o] + zt[n][o])
    const int lane = tx & 63;
    const int w    = tx >> 6;
    const float* y1b = y1t + (size_t)b * NPTS * 64;
    const float* ztb = zt  + (size_t)b * NPTS * 64;

    for (int rr = 0; rr < 8; ++rr) {
        const int rw = w*8 + rr;
        const int n  = n0 + rw;
        const float zv = ztb[(size_t)n*64 + lane];
        float acc = -INFINITY;
        #pragma unroll
        for (int k = 0; k < KNN; ++k) {
            const int m = ml[rw*20 + k];                 // LDS broadcast
            const float vv = y1b[(size_t)m*64 + lane];   // 256B row gather (L2)
            float h = vv + zv;
            h = fmaxf(h, 0.2f*h);                        // leaky relu, exact
            acc = fmaxf(acc, h);
        }
        outbuf[rw*68 + lane] = acc;
    }
    __syncthreads();
    float* ob = out + (size_t)b * OUTC * NPTS;
    #pragma unroll
    for (int qo = 0; qo < 8; ++qo) {
        const int o = w*16 + qo*2 + (lane >> 5);
        const int n = lane & 31;
        ob[(size_t)o*NPTS + n0 + n] = outbuf[n*68 + o];  // coalesced 128B segments
    }
}

extern "C" void kernel_launch(void* const* d_in, const int* in_sizes, int n_in,
                              void* d_out, int out_size, void* d_ws, size_t ws_size,
                              hipStream_t stream) {
    const float* x    = (const float*)d_in[0];   // (8,64,2048)
    const float* W    = (const float*)d_in[1];   // (64,128)
    const float* bias = (const float*)d_in[2];   // (64,)
    float* out = (float*)d_out;                  // (8,64,2048)

    // workspace: y1t (4MB) | zt (4MB) | xx (64KB)
    float* y1t = (float*)d_ws;
    float* zt  = y1t + (size_t)BATCH * NPTS * 64;
    float* xx  = zt  + (size_t)BATCH * NPTS * 64;

    edgeconv_prep<<<BATCH * (NPTS/32), 256, 0, stream>>>(x, W, bias, y1t, zt, xx);
    edgeconv_main<<<BATCH * (NPTS/32), 256, 0, stream>>>(x, y1t, zt, xx, out);
}

// Round 6
// 307.003 us; speedup vs baseline: 1.3361x; 1.3361x over previous
//
#include <hip/hip_runtime.h>
#include <math.h>

#define BATCH 8
#define CH    64
#define NPTS  2048
#define KNN   20
#define OUTC  64

// Branchless sorted insert (ascending d[0..19], d[0] = 20th best).
// Precondition: iv > d[0].
__device__ __forceinline__ void ladder20(float (&d)[KNN], int (&id)[KNN], float iv, int ii) {
    bool ci = true;
    #pragma unroll
    for (int s = 0; s < KNN; ++s) {
        const bool  cn = (s < KNN-1) ? (iv > d[s+1]) : false;
        const float dn = (s < KNN-1) ? d[s+1] : 0.f;
        const int   gn = (s < KNN-1) ? id[s+1] : 0;
        d[s]  = cn ? dn : (ci ? iv : d[s]);
        id[s] = cn ? gn : (ci ? ii : id[s]);
        ci = cn;
    }
}

// prep: 512 blocks, 32-m tiles.
// y1t[b][m][o] = W1 . x[:,m] ; zt[b][n][o] = (W2-W1) . x[:,n] + bias ; xx = ||x_m||^2
__global__ __launch_bounds__(256) void edgeconv_prep(
    const float* __restrict__ x, const float* __restrict__ W,
    const float* __restrict__ bias,
    float* __restrict__ y1t, float* __restrict__ zt, float* __restrict__ xx)
{
    __shared__ __align__(16) float Wt1[64*65];   // [c][o] pad 65 (conflict-free)
    __shared__ __align__(16) float Wtd[64*65];
    __shared__ __align__(16) float xs [64*32];   // [c][m]
    const int tx  = threadIdx.x;
    const int bid = blockIdx.x;
    const int b   = bid >> 6;
    const int m0  = (bid & 63) << 5;
    const float* xb = x + (size_t)b * (CH * NPTS);

    {   // stage W transposed (pad 65)
        const int o  = tx >> 2;
        const int cb = (tx & 3) << 4;
        #pragma unroll
        for (int cc = 0; cc < 16; cc += 4) {
            const float4 w1 = *(const float4*)&W[o*128 + cb + cc];
            const float4 w2 = *(const float4*)&W[o*128 + 64 + cb + cc];
            const float a1[4] = {w1.x, w1.y, w1.z, w1.w};
            const float a2[4] = {w2.x, w2.y, w2.z, w2.w};
            #pragma unroll
            for (int e = 0; e < 4; ++e) {
                Wt1[(cb+cc+e)*65 + o] = a1[e];
                Wtd[(cb+cc+e)*65 + o] = a2[e] - a1[e];
            }
        }
    }
    {   // stage x tile [64c][32m]
        const int c0 = tx >> 2;
        const int j0 = (tx & 3) << 3;
        *(float4*)&xs[c0*32 + j0]     = *(const float4*)&xb[(size_t)c0*NPTS + m0 + j0];
        *(float4*)&xs[c0*32 + j0 + 4] = *(const float4*)&xb[(size_t)c0*NPTS + m0 + j0 + 4];
    }
    __syncthreads();

    if (tx < 32) {   // squared norms
        float s = 0.f;
        #pragma unroll
        for (int c = 0; c < 64; ++c) { const float v = xs[c*32 + tx]; s = fmaf(v, v, s); }
        xx[b*NPTS + m0 + tx] = s;
    }

    const int o  = tx & 63;   // lane = output channel (coalesced writes)
    const int mg = tx >> 6;   // wave -> 8-m chunk
    float y[8], z[8];
    const float bo = bias[o];
    #pragma unroll
    for (int i = 0; i < 8; ++i) { y[i] = 0.f; z[i] = bo; }
    #pragma unroll 8
    for (int c = 0; c < 64; ++c) {
        const float w1 = Wt1[c*65 + o];
        const float wd = Wtd[c*65 + o];
        float a[8];
        *(float4*)&a[0] = *(const float4*)&xs[c*32 + mg*8];
        *(float4*)&a[4] = *(const float4*)&xs[c*32 + mg*8 + 4];
        #pragma unroll
        for (int i = 0; i < 8; ++i) {
            y[i] = fmaf(w1, a[i], y[i]);
            z[i] = fmaf(wd, a[i], z[i]);
        }
    }
    #pragma unroll
    for (int i = 0; i < 8; ++i) {
        const int m = m0 + mg*8 + i;
        y1t[((size_t)b*NPTS + m)*64 + o] = y[i];
        zt [((size_t)b*NPTS + m)*64 + o] = z[i];
    }
}

// Main: fused kNN + gather + lrelu + max. 512 blocks = (batch, 32-row tile).
// Rank key: 2*dot(n,m) - ||x_m||^2. Thread (r=tx>>3, q=tx&7) computes AND scans
// scores for row r, cols {q*4..+3} u {q*4+32..+35} of each 64-m tile.
// Bank-exact LDS patterns:
//   xnt [32][68]: float4 at r*68+c4 -> 8 distinct bank-quads {4r}, 8-lane bcast.
//   bufc b128 at c*64+q*4 (+32): 8 chunks at float offs {0,4..28} -> 32 banks once.
// Row-shared threshold thrR = max over row's 8 lanes of own 20th-best.
__global__ __launch_bounds__(256) void edgeconv_main(
    const float* __restrict__ x,
    const float* __restrict__ y1t, const float* __restrict__ zt,
    const float* __restrict__ xx, float* __restrict__ out)
{
    __shared__ __align__(16) char pool[43520];
    float* xnt = (float*)pool;              // [32r][68c]  8704 (pad 68: quad offset 4r)
    float* xmb = (float*)(pool + 8704);     // [2][64c][64m] 32768 (double buffer)
    float* xxb = (float*)(pool + 41472);    // [2][64]      512
    // phase-2 aliases (phase-1 data dead at first touch, barrier-separated):
    float* mv  = (float*)pool;              // [256 lanes][20] values
    int*   mi  = (int*)(pool + 20480);      // [256 lanes][20] indices
    int*   ml  = (int*)(pool + 40960);      // [32][20] merged knn idx
    float* outbuf = (float*)pool;           // [32][68] epilogue staging

    const int tx  = threadIdx.x;
    const int bid = blockIdx.x;
    const int b   = bid >> 6;
    const int n0  = (bid & 63) << 5;
    const float* xb = x + (size_t)b * (CH * NPTS);

    {   // stage xnt transposed [32r][68c]: lane (rr=tx>>3, c8=(tx&7)*8) writes 8 floats
        const int rr = tx >> 3;
        const int c8 = (tx & 7) << 3;
        #pragma unroll
        for (int i = 0; i < 8; ++i)
            xnt[rr*68 + c8 + i] = xb[(size_t)(c8 + i)*NPTS + n0 + rr];
    }
    {   // stage xm buffer 0 (m-tile 0) + xx
        const int c = tx >> 4;
        const int j = (tx & 15) << 2;
        #pragma unroll
        for (int it = 0; it < 4; ++it)
            *(float4*)&xmb[(c + it*16)*64 + j] = *(const float4*)&xb[(size_t)(c + it*16)*NPTS + j];
        if (tx < 64) xxb[tx] = xx[b*NPTS + tx];
    }

    const int r = tx >> 3;          // my row (0..31)
    const int q = tx & 7;           // my col-octet: cols q*4..+3 and q*4+32..+35
    float d[KNN]; int id[KNN];
    #pragma unroll
    for (int k = 0; k < KNN; ++k) { d[k] = -INFINITY; id[k] = 0; }
    float thrR = -INFINITY;

    for (int t = 0; t < 32; ++t) {
        __syncthreads();            // buf[cur] ready; all reads of buf[cur^1] from t-1 done
        const int cur = t & 1;
        const float* bufc = xmb + cur*4096;
        const float* xxc  = xxb + cur*64;
        float* bufn = xmb + (cur^1)*4096;
        float* xxn  = xxb + (cur^1)*64;

        // issue prefetch of next m-tile (global, latency hidden under Gram)
        float4 p0, p1, p2, p3;
        float xxp = 0.f;
        const int tn  = t + 1;
        const int jj  = (tx & 15) << 2;
        const int cc4 = tx >> 4;
        if (tn < 32) {
            const int mb2 = tn << 6;
            p0 = *(const float4*)&xb[(size_t)(cc4 +  0)*NPTS + mb2 + jj];
            p1 = *(const float4*)&xb[(size_t)(cc4 + 16)*NPTS + mb2 + jj];
            p2 = *(const float4*)&xb[(size_t)(cc4 + 32)*NPTS + mb2 + jj];
            p3 = *(const float4*)&xb[(size_t)(cc4 + 48)*NPTS + mb2 + jj];
            if (tx < 64) xxp = xx[b*NPTS + mb2 + tx];
        }

        // Gram: acc8[e] = dot(x_n[r], x_m[col(e)]), col(e) = q*4+(e&3)+((e&4)?32:0)
        float acc8[8];
        #pragma unroll
        for (int e = 0; e < 8; ++e) acc8[e] = 0.f;
        #pragma unroll 4
        for (int c4 = 0; c4 < 64; c4 += 4) {
            float av[4];
            *(float4*)&av[0] = *(const float4*)&xnt[r*68 + c4];
            #pragma unroll
            for (int i = 0; i < 4; ++i) {
                float bv[8];
                *(float4*)&bv[0] = *(const float4*)&bufc[(c4+i)*64 + q*4];
                *(float4*)&bv[4] = *(const float4*)&bufc[(c4+i)*64 + q*4 + 32];
                #pragma unroll
                for (int e = 0; e < 8; ++e) acc8[e] = fmaf(av[i], bv[e], acc8[e]);
            }
        }

        // keys + candidate mask (strict > : lax.top_k tie semantics)
        float xq[8];
        *(float4*)&xq[0] = *(const float4*)&xxc[q*4];
        *(float4*)&xq[4] = *(const float4*)&xxc[q*4 + 32];
        float v[8];
        unsigned msk = 0u;
        #pragma unroll
        for (int e = 0; e < 8; ++e) {
            v[e] = fmaf(2.f, acc8[e], -xq[e]);
            msk |= (v[e] > thrR) ? (1u << e) : 0u;
        }

        // drain: wave pays max-lane candidate count; values muxed from REGISTERS
        const int base = (t << 6) + (q << 2);
        while (__any(msk != 0u)) {
            const bool act = (msk != 0u);
            const int  e   = __ffs(msk) - 1;    // ascending e => ascending m (tie order)
            msk &= msk - 1u;
            const float t01 = (e & 1) ? v[1] : v[0];
            const float t23 = (e & 1) ? v[3] : v[2];
            const float t45 = (e & 1) ? v[5] : v[4];
            const float t67 = (e & 1) ? v[7] : v[6];
            const float t03 = (e & 2) ? t23 : t01;
            const float t47 = (e & 2) ? t67 : t45;
            const float vv  = (e & 4) ? t47 : t03;
            if (act && vv > d[0]) ladder20(d, id, vv, base + (e & 3) + ((e & 4) ? 32 : 0));
        }

        // row-shared threshold: max over the row's 8 lanes of own d[0]
        float tm = d[0];
        tm = fmaxf(tm, __shfl_xor(tm, 1));
        tm = fmaxf(tm, __shfl_xor(tm, 2));
        tm = fmaxf(tm, __shfl_xor(tm, 4));
        thrR = tm;

        if (tn < 32) {   // commit prefetched tile into the other buffer
            *(float4*)&bufn[(cc4 +  0)*64 + jj] = p0;
            *(float4*)&bufn[(cc4 + 16)*64 + jj] = p1;
            *(float4*)&bufn[(cc4 + 32)*64 + jj] = p2;
            *(float4*)&bufn[(cc4 + 48)*64 + jj] = p3;
            if (tx < 64) xxn[tx] = xxp;
        }
    }
    __syncthreads();   // all Gram reads done; pool reusable

    // dump per-lane sorted lists (scalar stores keep d/id in registers)
    #pragma unroll
    for (int k = 0; k < KNN; ++k) { mv[tx*20 + k] = d[k]; mi[tx*20 + k] = id[k]; }
    __syncthreads();

    // 8-head merge, one lane per row; comparator (v desc, idx asc) == lax.top_k
    if (q == 0) {
        float hv[8]; int hi[8]; int hp[8];
        #pragma unroll
        for (int s = 0; s < 8; ++s) {
            hp[s] = KNN - 1;
            hv[s] = mv[(r*8 + s)*20 + KNN - 1];
            hi[s] = mi[(r*8 + s)*20 + KNN - 1];
        }
        for (int k = 0; k < KNN; ++k) {
            float bv = hv[0]; int bg = hi[0]; int bs = 0;
            #pragma unroll
            for (int s = 1; s < 8; ++s) {
                const bool better = (hv[s] > bv) || (hv[s] == bv && hi[s] < bg);
                bv = better ? hv[s] : bv;
                bg = better ? hi[s] : bg;
                bs = better ? s : bs;
            }
            ml[r*20 + k] = bg;
            #pragma unroll
            for (int s = 0; s < 8; ++s) {     // static-index advance (rule #20)
                if (bs == s) {
                    const int np  = hp[s] - 1;
                    hp[s] = np;
                    const bool ok = (np >= 0);
                    const int npc = ok ? np : 0;
                    const float nv = mv[(r*8 + s)*20 + npc];
                    const int   ng = mi[(r*8 + s)*20 + npc];
                    hv[s] = ok ? nv : -INFINITY;
                    hi[s] = ok ? ng : 0;
                }
            }
        }
    }
    __syncthreads();

    // epilogue: out[b,o,n] = max_k lrelu(y1t[m_k][o] + zt[n][o])
    const int lane = tx & 63;
    const int w    = tx >> 6;
    const float* y1b = y1t + (size_t)b * NPTS * 64;
    const float* ztb = zt  + (size_t)b * NPTS * 64;

    for (int rr = 0; rr < 8; ++rr) {
        const int rw = w*8 + rr;
        const int n  = n0 + rw;
        const float zv = ztb[(size_t)n*64 + lane];
        float acc = -INFINITY;
        #pragma unroll
        for (int k = 0; k < KNN; ++k) {
            const int m = ml[rw*20 + k];                 // LDS broadcast
            const float vv = y1b[(size_t)m*64 + lane];   // 256B row gather (L2)
            float h = vv + zv;
            h = fmaxf(h, 0.2f*h);                        // leaky relu, exact
            acc = fmaxf(acc, h);
        }
        outbuf[rw*68 + lane] = acc;
    }
    __syncthreads();
    float* ob = out + (size_t)b * OUTC * NPTS;
    #pragma unroll
    for (int qo = 0; qo < 8; ++qo) {
        const int o = w*16 + qo*2 + (lane >> 5);
        const int n = lane & 31;
        ob[(size_t)o*NPTS + n0 + n] = outbuf[n*68 + o];  // coalesced 128B segments
    }
}

extern "C" void kernel_launch(void* const* d_in, const int* in_sizes, int n_in,
                              void* d_out, int out_size, void* d_ws, size_t ws_size,
                              hipStream_t stream) {
    const float* x    = (const float*)d_in[0];   // (8,64,2048)
    const float* W    = (const float*)d_in[1];   // (64,128)
    const float* bias = (const float*)d_in[2];   // (64,)
    float* out = (float*)d_out;                  // (8,64,2048)

    // workspace: y1t (4MB) | zt (4MB) | xx (64KB)
    float* y1t = (float*)d_ws;
    float* zt  = y1t + (size_t)BATCH * NPTS * 64;
    float* xx  = zt  + (size_t)BATCH * NPTS * 64;

    edgeconv_prep<<<BATCH * (NPTS/32), 256, 0, stream>>>(x, W, bias, y1t, zt, xx);
    edgeconv_main<<<BATCH * (NPTS/32), 256, 0, stream>>>(x, y1t, zt, xx, out);
}